// Round 6
// baseline (184.115 us; speedup 1.0000x reference)
//
#include <hip/hip_runtime.h>

#define V 50257
#define H 1024
#define NB 512
#define NWAVES (NB * 4)          // 2048 waves; 25 rows/wave over V

// ---- flag layout (ints), one counter block per stage ----
#define F_ALOG 0
#define F_AAPP 1
#define F_XBUF 2
#define F_G    3
#define F_LOG  4
#define CNT_STRIDE 320           // ints per counter: 8 slots @ s*32, done_cnt @256, done @288
#define FLAG_INTS (5 * CNT_STRIDE)

__device__ __forceinline__ float wave_reduce_sum(float v) {
    #pragma unroll
    for (int off = 32; off > 0; off >>= 1)
        v += __shfl_down(v, off, 64);
    return v;  // lane 0
}

__device__ __forceinline__ float dot1024(const float* __restrict__ Wr,
                                         const float4* __restrict__ v4, int lane) {
    const float4* w4 = (const float4*)Wr;
    float acc = 0.f;
    #pragma unroll
    for (int j = 0; j < 4; ++j) {
        float4 w = w4[lane + 64 * j];
        float4 x = v4[lane + 64 * j];
        acc += w.x * x.x + w.y * x.y + w.z * x.z + w.w * x.w;
    }
    return acc;
}

// Release + two-level count. SYSTEM scope => RMW at coherence point (never stale).
__device__ __forceinline__ void sig(int* flags, int cid, int perslot) {
    __syncthreads();
    if (threadIdx.x == 0) {
        __threadfence();  // release: flush this block's stores
        int* c = flags + cid * CNT_STRIDE;
        int old = __hip_atomic_fetch_add(c + (blockIdx.x & 7) * 32, 1,
                                         __ATOMIC_RELAXED, __HIP_MEMORY_SCOPE_SYSTEM);
        if (old == perslot - 1) {
            int o2 = __hip_atomic_fetch_add(c + 256, 1, __ATOMIC_RELAXED,
                                            __HIP_MEMORY_SCOPE_SYSTEM);
            if (o2 == 7)
                __hip_atomic_fetch_add(c + 288, 1, __ATOMIC_RELAXED,
                                       __HIP_MEMORY_SCOPE_SYSTEM);
        }
    }
}

// Poll ONE word at SYSTEM scope (cache-bypassing), sleep between polls; acquire after.
__device__ __forceinline__ void wtf(int* flags, int cid) {
    if (threadIdx.x == 0) {
        int* d = flags + cid * CNT_STRIDE + 288;
        while (__hip_atomic_load(d, __ATOMIC_RELAXED, __HIP_MEMORY_SCOPE_SYSTEM) == 0)
            __builtin_amdgcn_s_sleep(16);   // ~1024 cycles
    }
    __syncthreads();
    __threadfence();  // acquire: invalidate stale cached data
}

__global__ void __launch_bounds__(256, 2)
mega_kernel(const int* __restrict__ token, const float* __restrict__ hidden,
            const float* __restrict__ enc, const float* __restrict__ emb_table,
            const float* __restrict__ attn_w, const float* __restrict__ attn_b,
            const float* __restrict__ comb_w, const float* __restrict__ comb_b,
            const float* __restrict__ w_ih, const float* __restrict__ w_hh,
            const float* __restrict__ b_ih, const float* __restrict__ b_hh,
            const float* __restrict__ out_w, const float* __restrict__ out_b,
            float* __restrict__ out, float* __restrict__ hnew_out,
            float* __restrict__ attnw_out,
            float* __restrict__ alog, float* __restrict__ aapp,
            float* __restrict__ xbuf, float* __restrict__ g,
            float* __restrict__ part, int* flags) {
    __shared__ float sh[1024];
    __shared__ float sred[8];

    const int bx = blockIdx.x, t = threadIdx.x;
    const int wid = t >> 6, lane = t & 63;
    const float4* h4 = (const float4*)hidden;

    // ================= S0 =================
    if (bx < 128) {
        // attn logits: wave-per-row, 512 rows
        int row = bx * 4 + wid;
        const float* Wr = attn_w + (size_t)row * 2048;
        const float4* e4 = (const float4*)(emb_table + (size_t)(*token) * 1024);
        float acc = dot1024(Wr, e4, lane) + dot1024(Wr + 1024, h4, lane);
        acc = wave_reduce_sum(acc);
        if (lane == 0) alog[row] = acc + attn_b[row];
        sig(flags, F_ALOG, 16);
    } else if (bx < 320) {
        // gates-hh: 3072 rows, 4 rows/wave
        int r0 = ((bx - 128) * 4 + wid) * 4;
        #pragma unroll
        for (int i = 0; i < 4; ++i) {
            int row = r0 + i;
            float acc = dot1024(w_hh + (size_t)row * 1024, h4, lane);
            acc = wave_reduce_sum(acc);
            if (lane == 0) g[3072 + row] = acc + b_hh[row];
        }
        sig(flags, F_G, 48);
    }

    // ================= S1: softmax + apply (blocks 0..31) =================
    if (bx < 32) {
        wtf(flags, F_ALOG);
        float a0 = alog[t], a1 = alog[t + 256];
        float m = fmaxf(a0, a1);
        #pragma unroll
        for (int off = 32; off > 0; off >>= 1)
            m = fmaxf(m, __shfl_down(m, off, 64));
        if (lane == 0) sred[wid] = m;
        __syncthreads();
        float M = fmaxf(fmaxf(sred[0], sred[1]), fmaxf(sred[2], sred[3]));
        float e0 = expf(a0 - M), e1 = expf(a1 - M);
        sh[t] = e0; sh[t + 256] = e1;
        float s = wave_reduce_sum(e0 + e1);
        if (lane == 0) sred[4 + wid] = s;
        __syncthreads();                    // covers sh[0..512) and sred[4..8)
        float S = sred[4] + sred[5] + sred[6] + sred[7];
        if (bx == 0) {
            attnw_out[t] = sh[t] / S;
            attnw_out[t + 256] = sh[t + 256] / S;
        }
        // apply: this block covers cols [bx*32, bx*32+32); thread: col t&31, l-chunk t>>5
        int c  = bx * 32 + (t & 31);
        int l0 = (t >> 5) * 64;
        float acc = 0.f;
        #pragma unroll 8
        for (int l = 0; l < 64; ++l)
            acc += sh[l0 + l] * enc[(size_t)(l0 + l) * 1024 + c];
        sh[512 + t] = acc;                  // partials, disjoint from ebs
        __syncthreads();
        if (t < 32) {
            float s2 = 0.f;
            #pragma unroll
            for (int j = 0; j < 8; ++j) s2 += sh[512 + j * 32 + t];
            aapp[bx * 32 + t] = s2 / S;
        }
        sig(flags, F_AAPP, 4);
    }

    // ================= S2: combine + relu (blocks 0..127, 2 rows/wave) ======
    if (bx < 128) {
        wtf(flags, F_AAPP);
        const float4* e4 = (const float4*)(emb_table + (size_t)(*token) * 1024);
        const float4* a4 = (const float4*)aapp;
        int r0 = (bx * 4 + wid) * 2;
        #pragma unroll
        for (int i = 0; i < 2; ++i) {
            int row = r0 + i;
            const float* Wr = comb_w + (size_t)row * 2048;
            float acc = dot1024(Wr, e4, lane) + dot1024(Wr + 1024, a4, lane);
            acc = wave_reduce_sum(acc);
            if (lane == 0) xbuf[row] = fmaxf(acc + comb_b[row], 0.0f);
        }
        sig(flags, F_XBUF, 16);
    }

    // ================= S3: gates-ih (blocks 320..511, 4 rows/wave) ==========
    if (bx >= 320) {
        wtf(flags, F_XBUF);
        const float4* x4 = (const float4*)xbuf;
        int r0 = ((bx - 320) * 4 + wid) * 4;
        #pragma unroll
        for (int i = 0; i < 4; ++i) {
            int row = r0 + i;
            float acc = dot1024(w_ih + (size_t)row * 1024, x4, lane);
            acc = wave_reduce_sum(acc);
            if (lane == 0) g[row] = acc + b_ih[row];
        }
        sig(flags, F_G, 48);
    }

    // ================= S4: GRU (redundant) + logits (all blocks) ============
    wtf(flags, F_G);
    for (int j = t; j < 1024; j += 256) {
        float i_r = g[j], i_z = g[j + 1024], i_n = g[j + 2048];
        float h_r = g[3072 + j], h_z = g[4096 + j], h_n = g[5120 + j];
        float r = 1.0f / (1.0f + expf(-(i_r + h_r)));
        float z = 1.0f / (1.0f + expf(-(i_z + h_z)));
        float n = tanhf(i_n + r * h_n);
        float hv = (1.0f - z) * n + z * hidden[j];
        sh[j] = hv;
        if (bx == 0) hnew_out[j] = hv;
    }
    __syncthreads();

    const int gw = bx * 4 + wid;            // wave id in [0, 2048)
    float lgv = 0.0f;                       // lane k holds logit of row gw + k*2048
    {
        const float4* hh4 = (const float4*)sh;
        float4 x0 = hh4[lane], x1 = hh4[lane + 64], x2 = hh4[lane + 128], x3 = hh4[lane + 192];
        #pragma unroll
        for (int k = 0; k < 25; ++k) {
            int row = gw + (k << 11);
            if (row < V) {
                const float4* w4 = (const float4*)(out_w + (size_t)row * 1024);
                float4 w0 = w4[lane], w1 = w4[lane + 64], w2 = w4[lane + 128], w3 = w4[lane + 192];
                float acc = w0.x * x0.x + w0.y * x0.y + w0.z * x0.z + w0.w * x0.w
                          + w1.x * x1.x + w1.y * x1.y + w1.z * x1.z + w1.w * x1.w
                          + w2.x * x2.x + w2.y * x2.y + w2.z * x2.z + w2.w * x2.w
                          + w3.x * x3.x + w3.y * x3.y + w3.z * x3.z + w3.w * x3.w;
                acc = wave_reduce_sum(acc);
                float b = __shfl(acc, 0, 64) + out_b[row];
                if (lane == k) lgv = b;
            }
        }
        // partial sumexp: lane k holds row gw + k*2048
        int myrow = gw + (lane << 11);
        bool ok = (lane < 25) && (myrow < V);
        float pe = ok ? expf(lgv) : 0.0f;
        pe = wave_reduce_sum(pe);
        if (lane == 0) sred[wid] = pe;
        __syncthreads();
        if (t == 0) part[bx] = sred[0] + sred[1] + sred[2] + sred[3];
    }
    sig(flags, F_LOG, 64);

    // ================= S5: lse (redundant) + write out ======================
    wtf(flags, F_LOG);
    {
        float v = part[t] + part[t + 256];
        v = wave_reduce_sum(v);
        if (lane == 0) sred[wid] = v;
        __syncthreads();
        if (t == 0) sred[0] = logf(sred[0] + sred[1] + sred[2] + sred[3]);
        __syncthreads();
        float lse = sred[0];
        int myrow = gw + (lane << 11);
        if (lane < 25 && myrow < V) out[myrow] = lgv - lse;
    }
}

extern "C" void kernel_launch(void* const* d_in, const int* in_sizes, int n_in,
                              void* d_out, int out_size, void* d_ws, size_t ws_size,
                              hipStream_t stream) {
    const int*   token     = (const int*)d_in[0];
    const float* hidden    = (const float*)d_in[1];
    const float* enc       = (const float*)d_in[2];
    const float* emb_table = (const float*)d_in[3];
    const float* attn_w    = (const float*)d_in[4];
    const float* attn_b    = (const float*)d_in[5];
    const float* comb_w    = (const float*)d_in[6];
    const float* comb_b    = (const float*)d_in[7];
    const float* w_ih      = (const float*)d_in[8];
    const float* w_hh      = (const float*)d_in[9];
    const float* b_ih      = (const float*)d_in[10];
    const float* b_hh      = (const float*)d_in[11];
    const float* out_w     = (const float*)d_in[12];
    const float* out_b     = (const float*)d_in[13];

    float* out       = (float*)d_out;      // [V]
    float* hnew_out  = out + V;            // [H]
    float* attnw_out = out + V + H;        // [L]

    float* wsf  = (float*)d_ws;
    float* alog = wsf;                     // 512
    float* aapp = alog + 512;              // 1024
    float* xbuf = aapp + 1024;             // 1024
    float* g    = xbuf + 1024;             // 6144
    float* part = g + 6144;                // 512
    int*   flags = (int*)(part + 512);     // FLAG_INTS ints

    hipMemsetAsync(flags, 0, FLAG_INTS * sizeof(int), stream);

    void* args[] = {(void*)&token, (void*)&hidden, (void*)&enc, (void*)&emb_table,
                    (void*)&attn_w, (void*)&attn_b, (void*)&comb_w, (void*)&comb_b,
                    (void*)&w_ih, (void*)&w_hh, (void*)&b_ih, (void*)&b_hh,
                    (void*)&out_w, (void*)&out_b,
                    (void*)&out, (void*)&hnew_out, (void*)&attnw_out,
                    (void*)&alog, (void*)&aapp, (void*)&xbuf, (void*)&g,
                    (void*)&part, (void*)&flags};
    hipLaunchCooperativeKernel((void*)mega_kernel, dim3(NB), dim3(256), args, 0, stream);
}

// Round 7
// 55.995 us; speedup vs baseline: 3.2881x; 3.2881x over previous
//
#include <hip/hip_runtime.h>

#define V 50257
#define H 1024
#define E 1024
#define LENC 512
#define GBLK 2048            // blocks in logits kernel
#define GWAVES (GBLK * 4)

__device__ __forceinline__ float wave_reduce_sum(float v) {
    #pragma unroll
    for (int off = 32; off > 0; off >>= 1)
        v += __shfl_down(v, off, 64);
    return v;  // valid in lane 0
}

__device__ __forceinline__ float dot1024(const float* __restrict__ Wr,
                                         const float4* __restrict__ v4, int lane) {
    const float4* w4 = (const float4*)Wr;
    float acc = 0.f;
    #pragma unroll
    for (int j = 0; j < 4; ++j) {
        float4 w = w4[lane + 64 * j];
        float4 x = v4[lane + 64 * j];
        acc += w.x * x.x + w.y * x.y + w.z * x.z + w.w * x.w;
    }
    return acc;
}

// ---- A: attn logits (blocks 0..127) | gates-hh (128..895) | zero aapp (896)
__global__ void stageA_kernel(const float* __restrict__ attn_w,
                              const float* __restrict__ attn_b,
                              const float* __restrict__ w_hh,
                              const float* __restrict__ b_hh,
                              const float* __restrict__ emb_table,
                              const int*   __restrict__ token,
                              const float* __restrict__ hidden,
                              float* __restrict__ alog,
                              float* __restrict__ g,
                              float* __restrict__ aapp) {
    int bx = blockIdx.x;
    int wid = threadIdx.x >> 6, lane = threadIdx.x & 63;
    const float4* h4 = (const float4*)hidden;
    if (bx < 128) {
        int row = bx * 4 + wid;
        const float* Wr = attn_w + (size_t)row * 2048;
        const float4* e4 = (const float4*)(emb_table + (size_t)(*token) * 1024);
        float acc = dot1024(Wr, e4, lane) + dot1024(Wr + 1024, h4, lane);
        acc = wave_reduce_sum(acc);
        if (lane == 0) alog[row] = acc + attn_b[row];
    } else if (bx < 896) {
        int row = (bx - 128) * 4 + wid;          // 0..3071
        float acc = dot1024(w_hh + (size_t)row * 1024, h4, lane);
        acc = wave_reduce_sum(acc);
        if (lane == 0) g[3072 + row] = acc + b_hh[row];
    } else {
        int t = threadIdx.x;
        aapp[t] = 0.f; aapp[256 + t] = 0.f; aapp[512 + t] = 0.f; aapp[768 + t] = 0.f;
    }
}

// ---- C: redundant softmax per block + attn apply (256 blocks)
__global__ void stageC_kernel(const float* __restrict__ alog,
                              const float* __restrict__ enc,
                              float* __restrict__ aapp,
                              float* __restrict__ attnw_out) {
    int bx = blockIdx.x;
    int t = threadIdx.x;
    int lane = t & 63, wid = t >> 6;
    __shared__ float eb[512];
    __shared__ float sm[4], ssum[4];
    float a0 = alog[t], a1 = alog[t + 256];
    float m = fmaxf(a0, a1);
    #pragma unroll
    for (int off = 32; off > 0; off >>= 1)
        m = fmaxf(m, __shfl_down(m, off, 64));
    if (lane == 0) sm[wid] = m;
    __syncthreads();
    float M = fmaxf(fmaxf(sm[0], sm[1]), fmaxf(sm[2], sm[3]));
    float e0 = expf(a0 - M), e1 = expf(a1 - M);
    eb[t] = e0; eb[t + 256] = e1;
    float s = wave_reduce_sum(e0 + e1);
    if (lane == 0) ssum[wid] = s;
    __syncthreads();                 // covers eb[] and ssum[]
    float S = ssum[0] + ssum[1] + ssum[2] + ssum[3];
    if (bx == 0) {
        attnw_out[t] = eb[t] / S;
        attnw_out[t + 256] = eb[t + 256] / S;
    }
    // apply: block -> (h-chunk = bx&3, l-chunk of 8 = bx>>2)
    int h  = (bx & 3) * 256 + t;
    int l0 = (bx >> 2) * 8;
    float acc = 0.f;
    #pragma unroll
    for (int l = 0; l < 8; ++l)
        acc += eb[l0 + l] * enc[(size_t)(l0 + l) * 1024 + h];
    atomicAdd(&aapp[h], acc / S);
}

// ---- D: combine + relu (256 blocks, wave-per-row)
__global__ void stageD_kernel(const float* __restrict__ comb_w,
                              const float* __restrict__ comb_b,
                              const float* __restrict__ emb_table,
                              const int*   __restrict__ token,
                              const float* __restrict__ aapp,
                              float* __restrict__ xbuf) {
    int bx = blockIdx.x;
    int wid = threadIdx.x >> 6, lane = threadIdx.x & 63;
    int row = bx * 4 + wid;
    const float* Wr = comb_w + (size_t)row * 2048;
    const float4* e4 = (const float4*)(emb_table + (size_t)(*token) * 1024);
    float acc = dot1024(Wr, e4, lane) + dot1024(Wr + 1024, (const float4*)aapp, lane);
    acc = wave_reduce_sum(acc);
    if (lane == 0) xbuf[row] = fmaxf(acc + comb_b[row], 0.0f);
}

// ---- E: gates-ih triplet + fused GRU (256 blocks; wave per h-index j)
// Wave j computes the three w_ih gate rows (j, j+1024, j+2048) with
// interleaved loads (12 outstanding float4 per iteration = 3x MLP), reads the
// hh gates written by stage A (ordering guaranteed by kernel boundary), and
// writes h_new[j] directly (final output #2).
__global__ void stageE_gru_kernel(const float* __restrict__ w_ih,
                                  const float* __restrict__ b_ih,
                                  const float* __restrict__ xbuf,
                                  const float* __restrict__ g,
                                  const float* __restrict__ hidden,
                                  float* __restrict__ hnew_out) {
    int wid = threadIdx.x >> 6, lane = threadIdx.x & 63;
    int j = blockIdx.x * 4 + wid;            // 0..1023
    const float4* x4  = (const float4*)xbuf;
    const float4* wr4 = (const float4*)(w_ih + (size_t)j * 1024);
    const float4* wz4 = (const float4*)(w_ih + (size_t)(j + 1024) * 1024);
    const float4* wn4 = (const float4*)(w_ih + (size_t)(j + 2048) * 1024);
    float ar = 0.f, az = 0.f, an = 0.f;
    #pragma unroll
    for (int jj = 0; jj < 4; ++jj) {
        float4 x  = x4[lane + 64 * jj];
        float4 wr = wr4[lane + 64 * jj];
        float4 wz = wz4[lane + 64 * jj];
        float4 wn = wn4[lane + 64 * jj];
        ar += wr.x * x.x + wr.y * x.y + wr.z * x.z + wr.w * x.w;
        az += wz.x * x.x + wz.y * x.y + wz.z * x.z + wz.w * x.w;
        an += wn.x * x.x + wn.y * x.y + wn.z * x.z + wn.w * x.w;
    }
    ar = wave_reduce_sum(ar);
    az = wave_reduce_sum(az);
    an = wave_reduce_sum(an);
    if (lane == 0) {
        float i_r = ar + b_ih[j];
        float i_z = az + b_ih[j + 1024];
        float i_n = an + b_ih[j + 2048];
        float h_r = g[3072 + j], h_z = g[4096 + j], h_n = g[5120 + j];
        float r = 1.0f / (1.0f + expf(-(i_r + h_r)));
        float z = 1.0f / (1.0f + expf(-(i_z + h_z)));
        float n = tanhf(i_n + r * h_n);
        hnew_out[j] = (1.0f - z) * n + z * hidden[j];
    }
}

// ---- G: load h (4 KB, L2-hot) into LDS, then logits + partial sumexp
__global__ void logits_kernel(const float* __restrict__ hnew,
                              const float* __restrict__ out_w,
                              const float* __restrict__ out_b,
                              float* __restrict__ logits,
                              float* __restrict__ part) {
    __shared__ float4 hsm4[256];
    int t = threadIdx.x;
    hsm4[t] = ((const float4*)hnew)[t];
    __syncthreads();
    int wid = t >> 6, lane = t & 63;
    const float4* h4 = (const float4*)hsm4;
    float4 x0 = h4[lane], x1 = h4[lane + 64], x2 = h4[lane + 128], x3 = h4[lane + 192];
    float psum = 0.f;
    for (int row = blockIdx.x * 4 + wid; row < V; row += GWAVES) {
        const float4* w4 = (const float4*)(out_w + (size_t)row * 1024);
        float4 w0 = w4[lane], w1 = w4[lane + 64], w2 = w4[lane + 128], w3 = w4[lane + 192];
        float acc = w0.x * x0.x + w0.y * x0.y + w0.z * x0.z + w0.w * x0.w
                  + w1.x * x1.x + w1.y * x1.y + w1.z * x1.z + w1.w * x1.w
                  + w2.x * x2.x + w2.y * x2.y + w2.z * x2.z + w2.w * x2.w
                  + w3.x * x3.x + w3.y * x3.y + w3.z * x3.z + w3.w * x3.w;
        acc = wave_reduce_sum(acc);
        if (lane == 0) {
            acc += out_b[row];
            logits[row] = acc;
            psum += expf(acc);   // logits ~ +-5 with 0.02-scale weights: fp32-safe unshifted
        }
    }
    __shared__ float s[4];
    if (lane == 0) s[wid] = psum;
    __syncthreads();
    if (t == 0) part[blockIdx.x] = s[0] + s[1] + s[2] + s[3];
}

// ---- H: reduce part (L2-hot) -> lse; subtract in place
__global__ void logsub_kernel(float* __restrict__ out,
                              const float* __restrict__ part) {
    int t = threadIdx.x;
    int lane = t & 63, wid = t >> 6;
    float v = 0.f;
    #pragma unroll
    for (int i = 0; i < 8; ++i) v += part[t + 256 * i];
    v = wave_reduce_sum(v);
    __shared__ float s[4];
    if (lane == 0) s[wid] = v;
    __syncthreads();
    float lse = logf(s[0] + s[1] + s[2] + s[3]);
    int i = blockIdx.x * 256 + t;
    if (i < V) out[i] -= lse;
}

extern "C" void kernel_launch(void* const* d_in, const int* in_sizes, int n_in,
                              void* d_out, int out_size, void* d_ws, size_t ws_size,
                              hipStream_t stream) {
    const int*   token     = (const int*)d_in[0];
    const float* hidden    = (const float*)d_in[1];
    const float* enc       = (const float*)d_in[2];
    const float* emb_table = (const float*)d_in[3];
    const float* attn_w    = (const float*)d_in[4];
    const float* attn_b    = (const float*)d_in[5];
    const float* comb_w    = (const float*)d_in[6];
    const float* comb_b    = (const float*)d_in[7];
    const float* w_ih      = (const float*)d_in[8];
    const float* w_hh      = (const float*)d_in[9];
    const float* b_ih      = (const float*)d_in[10];
    const float* b_hh      = (const float*)d_in[11];
    const float* out_w     = (const float*)d_in[12];
    const float* out_b     = (const float*)d_in[13];

    float* out       = (float*)d_out;      // [V]
    float* hnew_out  = out + V;            // [H]
    float* attnw_out = out + V + H;        // [L]

    float* wsf  = (float*)d_ws;
    float* alog = wsf;                     // 512
    float* aapp = alog + 512;              // 1024
    float* xbuf = aapp + 1024;             // 1024
    float* g    = xbuf + 1024;             // 6144 (only [3072,6144) = hh gates used)
    float* part = g + 6144;                // GBLK

    // A: attn logits | gates-hh | zero aapp
    stageA_kernel<<<897, 256, 0, stream>>>(attn_w, attn_b, w_hh, b_hh, emb_table,
                                           token, hidden, alog, g, aapp);
    // C: softmax (redundant per block) + apply -> aapp; attn_weights out
    stageC_kernel<<<256, 256, 0, stream>>>(alog, enc, aapp, attnw_out);
    // D: combine + relu -> xbuf
    stageD_kernel<<<256, 256, 0, stream>>>(comb_w, comb_b, emb_table, token, aapp,
                                           xbuf);
    // E: gates-ih triplets + GRU -> h_new (final output #2)
    stageE_gru_kernel<<<256, 256, 0, stream>>>(w_ih, b_ih, xbuf, g, hidden,
                                               hnew_out);
    // G: logits + partial sumexp
    logits_kernel<<<GBLK, 256, 0, stream>>>(hnew_out, out_w, out_b, out, part);
    // H: lse + subtract
    logsub_kernel<<<(V + 255) / 256, 256, 0, stream>>>(out, part);
}